// Round 4
// baseline (430.735 us; speedup 1.0000x reference)
//
#include <hip/hip_runtime.h>

// BrickVectorEdgeModel on MI355X (gfx950).
// R4: R3's occupancy (64-row tiles, 2 blocks/CU, 16 waves/CU) + R2's ILP.
// Only the GLOBAL operand (wF, ~200-300 cyc L2 latency) is register
// double-buffered; eF comes JIT from LDS (fine-grained lgkmcnt is cheap).
// Reg budget: acc 64 + wF 32 + eF 16 + addr ~12 <= 128 -> 4 waves/SIMD.

typedef short  short8  __attribute__((ext_vector_type(8)));
typedef short  short4v __attribute__((ext_vector_type(4)));
typedef float  f32x4   __attribute__((ext_vector_type(4)));

#define LDSW 520   // LDS row stride in bf16 elems (520*2B = 1040B, 16B-aligned)

__device__ inline unsigned short f2bf(float x) {
  unsigned u = __float_as_uint(x);
  unsigned r = (u + 0x7FFFu + ((u >> 16) & 1u)) >> 16;  // RNE
  return (unsigned short)r;
}

template <int MT, int NT>
__device__ inline void zero_acc(f32x4 (&acc)[MT][NT]) {
#pragma unroll
  for (int mt = 0; mt < MT; ++mt)
#pragma unroll
    for (int nt = 0; nt < NT; ++nt) {
      f32x4 z = {0.f, 0.f, 0.f, 0.f};
      acc[mt][nt] = z;
    }
}

// acc[mt][nt] (+)= W-tile x E-tile.  W as MFMA A-operand (m = out-col),
// E as B-operand (n = edge-row).  Lane holds 4 consecutive out-cols
// (kg*4+r) at edge-row (mt*16 + (lane&15)).
// wF (global) double-buffered: loads for ks+1 issue BEFORE ks's MFMAs so
// vmcnt never drains to 0 inside the loop.  eF JIT from LDS.
template <int MT, int NT>
__device__ inline void gemm_kloop(const short* E, const short* __restrict__ W,
                                  int lane, int nbase, f32x4 (&acc)[MT][NT]) {
  const int mrow = lane & 15, kg = lane >> 4;
  const short* El = E + mrow * LDSW + kg * 8;
  const short* Wl = W + (nbase + mrow) * 512 + kg * 8;
  short8 wF[2][NT];
#pragma unroll
  for (int nt = 0; nt < NT; ++nt) wF[0][nt] = *(const short8*)(Wl + nt * 16 * 512);
#pragma unroll
  for (int ks = 0; ks < 16; ++ks) {
    const int cur = ks & 1, nxt = cur ^ 1;
    if (ks < 15) {
      const int k1 = (ks + 1) * 32;
#pragma unroll
      for (int nt = 0; nt < NT; ++nt)
        wF[nxt][nt] = *(const short8*)(Wl + nt * 16 * 512 + k1);
    }
    short8 eF[MT];
    const int k0 = ks * 32;
#pragma unroll
    for (int mt = 0; mt < MT; ++mt)
      eF[mt] = *(const short8*)(El + mt * 16 * LDSW + k0);
#pragma unroll
    for (int mt = 0; mt < MT; ++mt)
#pragma unroll
      for (int nt = 0; nt < NT; ++nt)
        acc[mt][nt] = __builtin_amdgcn_mfma_f32_16x16x32_bf16(
            wF[cur][nt], eF[mt], acc[mt][nt], 0, 0, 0);
  }
}

// relu(acc + bias[outcol]) -> bf16 -> LDS, 8B vector writes.
template <int MT, int NT>
__device__ inline void store_relu_lds(short* E, const float* __restrict__ bias,
                                      int lane, int nbase, f32x4 (&acc)[MT][NT]) {
  const int mrow = lane & 15, kg = lane >> 4;
#pragma unroll
  for (int nt = 0; nt < NT; ++nt) {
    const int oc = nbase + nt * 16 + kg * 4;
    const float4 bs = *(const float4*)(bias + oc);
#pragma unroll
    for (int mt = 0; mt < MT; ++mt) {
      short4v s;
      s.x = (short)f2bf(fmaxf(acc[mt][nt][0] + bs.x, 0.f));
      s.y = (short)f2bf(fmaxf(acc[mt][nt][1] + bs.y, 0.f));
      s.z = (short)f2bf(fmaxf(acc[mt][nt][2] + bs.z, 0.f));
      s.w = (short)f2bf(fmaxf(acc[mt][nt][3] + bs.w, 0.f));
      *(short4v*)&E[(mt * 16 + mrow) * LDSW + oc] = s;
    }
  }
}

// ---------------- prep: convert weights to bf16 in workspace ----------------
__global__ void prep_kernel(const float* __restrict__ Wa, const float* __restrict__ Wb,
                            const float* __restrict__ Wca, const float* __restrict__ Wcb,
                            const float* __restrict__ Wcc, const float* __restrict__ Wout,
                            short* __restrict__ outS) {
  const int tid = blockIdx.x * blockDim.x + threadIdx.x;
  const int stride = gridDim.x * blockDim.x;
  const int M = 262144;
  for (int i = tid; i < 6 * M + 1024; i += stride) {
    float x;
    if (i < M) x = Wa[i];
    else if (i < 2 * M) x = Wb[i - M];
    else if (i < 3 * M) { const int t = i - 2 * M; x = Wca[(t >> 9) * 1024 + (t & 511)]; }
    else if (i < 4 * M) { const int t = i - 3 * M; x = Wca[(t >> 9) * 1024 + 512 + (t & 511)]; }
    else if (i < 5 * M) x = Wcb[i - 4 * M];
    else if (i < 6 * M) x = Wcc[i - 5 * M];
    else x = Wout[i - 6 * M];
    outS[i] = (short)f2bf(x);
  }
}

// ---------------- node stage: f1 -> f2 -> u,v (48 WGs x 16 nodes) ----------------
__global__ __launch_bounds__(512, 2) void node_kernel(
    const float* __restrict__ bv, const float* __restrict__ xy,
    const float* __restrict__ Wxy, const float* __restrict__ bxy,
    const float* __restrict__ ba, const float* __restrict__ bb,
    const short* __restrict__ Wa, const short* __restrict__ Wb,
    const short* __restrict__ W1, const short* __restrict__ W2,
    float* __restrict__ u, float* __restrict__ v) {
  __shared__ short A[16 * LDSW];
  __shared__ float xyl[32];
  const int tid = threadIdx.x, lane = tid & 63, wave = tid >> 6;
  const int node0 = blockIdx.x * 16;

  {  // stage bv tile -> bf16 LDS
    const int hc = (tid & 127) * 4, m0 = tid >> 7;
#pragma unroll
    for (int m = m0; m < 16; m += 4) {
      const float4 t = *(const float4*)(bv + (node0 + m) * 512 + hc);
      short4v s;
      s.x = (short)f2bf(t.x); s.y = (short)f2bf(t.y);
      s.z = (short)f2bf(t.z); s.w = (short)f2bf(t.w);
      *(short4v*)&A[m * LDSW + hc] = s;
    }
    if (tid < 32) xyl[tid] = xy[node0 * 2 + tid];
  }
  __syncthreads();

  const int mrow = lane & 15, kg = lane >> 4, nbase = wave * 64;
  f32x4 acc[1][4];

  // layer 1: relu(bv@Wa^T + xy@Wxy^T + ba + bxy)
  zero_acc<1, 4>(acc);
  gemm_kloop<1, 4>(A, Wa, lane, nbase, acc);
  __syncthreads();
  {
    const float x0 = xyl[mrow * 2], x1 = xyl[mrow * 2 + 1];
#pragma unroll
    for (int nt = 0; nt < 4; ++nt) {
      const int oc = nbase + nt * 16 + kg * 4;
      const float4 b1 = *(const float4*)(ba + oc);
      const float4 b2 = *(const float4*)(bxy + oc);
      short4v s;
#pragma unroll
      for (int r = 0; r < 4; ++r) {
        const float w0 = Wxy[(oc + r) * 2], w1 = Wxy[(oc + r) * 2 + 1];
        const float bsr = (r == 0 ? b1.x + b2.x : r == 1 ? b1.y + b2.y
                          : r == 2 ? b1.z + b2.z : b1.w + b2.w);
        const float xv = fmaxf(acc[0][nt][r] + bsr + x0 * w0 + x1 * w1, 0.f);
        ((short*)&s)[r] = (short)f2bf(xv);
      }
      *(short4v*)&A[mrow * LDSW + oc] = s;
    }
  }
  __syncthreads();

  // layer 2: relu(f1@Wb^T + bb)
  zero_acc<1, 4>(acc);
  gemm_kloop<1, 4>(A, Wb, lane, nbase, acc);
  __syncthreads();
  store_relu_lds<1, 4>(A, bb, lane, nbase, acc);
  __syncthreads();

  // u = f2@W1^T (fp32), v = f2@W2^T
  zero_acc<1, 4>(acc);
  gemm_kloop<1, 4>(A, W1, lane, nbase, acc);
#pragma unroll
  for (int nt = 0; nt < 4; ++nt) {
    const int oc = nbase + nt * 16 + kg * 4;
    *(f32x4*)&u[(node0 + mrow) * 512 + oc] = acc[0][nt];
  }
  zero_acc<1, 4>(acc);
  gemm_kloop<1, 4>(A, W2, lane, nbase, acc);
#pragma unroll
  for (int nt = 0; nt < 4; ++nt) {
    const int oc = nbase + nt * 16 + kg * 4;
    *(f32x4*)&v[(node0 + mrow) * 512 + oc] = acc[0][nt];
  }
}

// ---------------- edge stage: fused E0 -> E1 -> E2 -> out ----------------
// 64-row tiles: LDS 70.7 KB -> 2 blocks/CU; regs <=128 -> 16 waves/CU.
__global__ __launch_bounds__(512, 4) void edge_kernel(
    const float* __restrict__ u, const float* __restrict__ v,
    const short* __restrict__ Wcb, const short* __restrict__ Wcc,
    const short* __restrict__ Wout,
    const float* __restrict__ bca, const float* __restrict__ bcb,
    const float* __restrict__ bcc, const float* __restrict__ bout,
    float* __restrict__ out) {
  __shared__ short A[64 * LDSW];       // 66560 B
  __shared__ float red[64 * 2 * 8];    //  4096 B
  const int tid = threadIdx.x, lane = tid & 63, wave = tid >> 6;
  const int blk = blockIdx.x;
  const int b = blk / 576, rem = blk % 576, i = rem / 3, jt = rem % 3;
  const float* urow0 = u + (b * 192 + jt * 64) * 512;  // e0 row m uses u[b, jt*64+m]
  const float* vrow  = v + (b * 192 + i) * 512;

  {  // Phase 0: E0 = relu(u[j] + v[i] + b_ca) -> bf16 LDS
    const int hc = (tid & 127) * 4, m0 = tid >> 7;
    const float4 vv = *(const float4*)(vrow + hc);
    const float4 bb = *(const float4*)(bca + hc);
#pragma unroll 4
    for (int m = m0; m < 64; m += 4) {
      const float4 uu = *(const float4*)(urow0 + m * 512 + hc);
      short4v s;
      s.x = (short)f2bf(fmaxf(uu.x + vv.x + bb.x, 0.f));
      s.y = (short)f2bf(fmaxf(uu.y + vv.y + bb.y, 0.f));
      s.z = (short)f2bf(fmaxf(uu.z + vv.z + bb.z, 0.f));
      s.w = (short)f2bf(fmaxf(uu.w + vv.w + bb.w, 0.f));
      *(short4v*)&A[m * LDSW + hc] = s;
    }
  }
  __syncthreads();

  const int nbase = wave * 64;
  f32x4 acc[4][4];

  // layer cb
  zero_acc<4, 4>(acc);
  gemm_kloop<4, 4>(A, Wcb, lane, nbase, acc);
  __syncthreads();                 // all waves done reading E0
  store_relu_lds<4, 4>(A, bcb, lane, nbase, acc);
  __syncthreads();

  // layer cc
  zero_acc<4, 4>(acc);
  gemm_kloop<4, 4>(A, Wcc, lane, nbase, acc);
  __syncthreads();
  store_relu_lds<4, 4>(A, bcc, lane, nbase, acc);
  __syncthreads();

  // final: out = E2 @ Wout^T + bout.  k-split across 8 waves, n padded 2->16.
  f32x4 oacc[4];
#pragma unroll
  for (int mt = 0; mt < 4; ++mt) { f32x4 z = {0.f, 0.f, 0.f, 0.f}; oacc[mt] = z; }
  const int n = lane & 15, kg2 = lane >> 4;
#pragma unroll
  for (int kk = 0; kk < 2; ++kk) {
    const int k0 = wave * 64 + kk * 32 + kg2 * 8;
    short8 bf = {0, 0, 0, 0, 0, 0, 0, 0};
    if (n < 2) bf = *(const short8*)(Wout + n * 512 + k0);
#pragma unroll
    for (int mt = 0; mt < 4; ++mt) {
      const short8 af = *(const short8*)(A + (mt * 16 + n) * LDSW + k0);
      oacc[mt] = __builtin_amdgcn_mfma_f32_16x16x32_bf16(af, bf, oacc[mt], 0, 0, 0);
    }
  }
  if (n < 2) {
#pragma unroll
    for (int mt = 0; mt < 4; ++mt)
#pragma unroll
      for (int r = 0; r < 4; ++r) {
        const int row = mt * 16 + kg2 * 4 + r;
        red[(row * 2 + n) * 8 + wave] = oacc[mt][r];
      }
  }
  __syncthreads();
  if (tid < 128) {
    const int row = tid >> 1, o = tid & 1;
    float s = bout[o];
#pragma unroll
    for (int w = 0; w < 8; ++w) s += red[(row * 2 + o) * 8 + w];
    out[((b * 192 + i) * 192 + jt * 64 + row) * 2 + o] = s;
  }
}

extern "C" void kernel_launch(void* const* d_in, const int* in_sizes, int n_in,
                              void* d_out, int out_size, void* d_ws, size_t ws_size,
                              hipStream_t stream) {
  const float* bv   = (const float*)d_in[0];
  const float* xy   = (const float*)d_in[1];
  const float* Wxy  = (const float*)d_in[2];
  const float* bxy  = (const float*)d_in[3];
  const float* Wa   = (const float*)d_in[4];
  const float* ba   = (const float*)d_in[5];
  const float* Wb   = (const float*)d_in[6];
  const float* bb   = (const float*)d_in[7];
  const float* Wca  = (const float*)d_in[8];
  const float* bca  = (const float*)d_in[9];
  const float* Wcb  = (const float*)d_in[10];
  const float* bcb  = (const float*)d_in[11];
  const float* Wcc  = (const float*)d_in[12];
  const float* bcc  = (const float*)d_in[13];
  const float* Wout = (const float*)d_in[14];
  const float* bout = (const float*)d_in[15];
  float* out = (float*)d_out;

  // ws layout: bf16 weights [0, ~3MB), u fp32 @ 4MB, v fp32 @ 4MB+1.5MB
  short* S = (short*)d_ws;
  short* WaB   = S;
  short* WbB   = S + 262144;
  short* W1B   = S + 524288;
  short* W2B   = S + 786432;
  short* WcbB  = S + 1048576;
  short* WccB  = S + 1310720;
  short* WoutB = S + 1572864;
  float* u = (float*)((char*)d_ws + (4u << 20));
  float* v = u + 393216;

  prep_kernel<<<512, 256, 0, stream>>>(Wa, Wb, Wca, Wcb, Wcc, Wout, S);
  node_kernel<<<48, 512, 0, stream>>>(bv, xy, Wxy, bxy, ba, bb, WaB, WbB, W1B, W2B, u, v);
  edge_kernel<<<2304, 512, 0, stream>>>(u, v, WcbB, WccB, WoutB, bca, bcb, bcc, bout, out);
}

// Round 5
// 300.062 us; speedup vs baseline: 1.4355x; 1.4355x over previous
//
#include <hip/hip_runtime.h>

// BrickVectorEdgeModel on MI355X (gfx950).
// R5: W-traffic attack. Model (fits R1-R4): edge time = W-bytes-per-CU at
// ~10-12 B/cyc/CU VMEM ceiling. So: 144-row edge tiles (3i x 48j, LDS 159KB,
// 1024 blocks = 4.0 full CU-rounds, W/CU 9->4.1 MB) with W-dbuf that actually
// fits at 2 waves/SIMD (256-reg budget). Node stage split into 3 per-layer
// 64x64-tiled kernels (W per block 2MB -> 64KB, all CUs busy).

typedef short  short8  __attribute__((ext_vector_type(8)));
typedef short  short4v __attribute__((ext_vector_type(4)));
typedef float  f32x4   __attribute__((ext_vector_type(4)));

#define LDSW 520   // LDS row stride in bf16 elems (520*2B = 1040B, 16B-aligned)

__device__ inline unsigned short f2bf(float x) {
  unsigned u = __float_as_uint(x);
  unsigned r = (u + 0x7FFFu + ((u >> 16) & 1u)) >> 16;  // RNE
  return (unsigned short)r;
}

template <int MT, int NT>
__device__ inline void zero_acc(f32x4 (&acc)[MT][NT]) {
#pragma unroll
  for (int mt = 0; mt < MT; ++mt)
#pragma unroll
    for (int nt = 0; nt < NT; ++nt) {
      f32x4 z = {0.f, 0.f, 0.f, 0.f};
      acc[mt][nt] = z;
    }
}

// acc[mt][nt] (+)= W-tile x E-tile.  W as MFMA A-operand (m = out-col),
// E as B-operand (n = edge-row).  Lane holds 4 consecutive out-cols
// (kg*4+r) at edge-row (mt*16 + (lane&15)).
// wF (global, ~200-300cyc) register double-buffered; eF JIT from LDS.
template <int MT, int NT>
__device__ inline void gemm_kloop(const short* E, const short* __restrict__ W,
                                  int lane, int nbase, f32x4 (&acc)[MT][NT]) {
  const int mrow = lane & 15, kg = lane >> 4;
  const short* El = E + mrow * LDSW + kg * 8;
  const short* Wl = W + (nbase + mrow) * 512 + kg * 8;
  short8 wF[2][NT];
#pragma unroll
  for (int nt = 0; nt < NT; ++nt) wF[0][nt] = *(const short8*)(Wl + nt * 16 * 512);
#pragma unroll
  for (int ks = 0; ks < 16; ++ks) {
    const int cur = ks & 1, nxt = cur ^ 1;
    if (ks < 15) {
      const int k1 = (ks + 1) * 32;
#pragma unroll
      for (int nt = 0; nt < NT; ++nt)
        wF[nxt][nt] = *(const short8*)(Wl + nt * 16 * 512 + k1);
    }
    short8 eF[MT];
    const int k0 = ks * 32;
#pragma unroll
    for (int mt = 0; mt < MT; ++mt)
      eF[mt] = *(const short8*)(El + mt * 16 * LDSW + k0);
#pragma unroll
    for (int mt = 0; mt < MT; ++mt)
#pragma unroll
      for (int nt = 0; nt < NT; ++nt)
        acc[mt][nt] = __builtin_amdgcn_mfma_f32_16x16x32_bf16(
            wF[cur][nt], eF[mt], acc[mt][nt], 0, 0, 0);
  }
}

// relu(acc + bias[outcol]) -> bf16 -> LDS, 8B vector writes.
template <int MT, int NT>
__device__ inline void store_relu_lds(short* E, const float* __restrict__ bias,
                                      int lane, int nbase, f32x4 (&acc)[MT][NT]) {
  const int mrow = lane & 15, kg = lane >> 4;
#pragma unroll
  for (int nt = 0; nt < NT; ++nt) {
    const int oc = nbase + nt * 16 + kg * 4;
    const float4 bs = *(const float4*)(bias + oc);
#pragma unroll
    for (int mt = 0; mt < MT; ++mt) {
      short4v s;
      s.x = (short)f2bf(fmaxf(acc[mt][nt][0] + bs.x, 0.f));
      s.y = (short)f2bf(fmaxf(acc[mt][nt][1] + bs.y, 0.f));
      s.z = (short)f2bf(fmaxf(acc[mt][nt][2] + bs.z, 0.f));
      s.w = (short)f2bf(fmaxf(acc[mt][nt][3] + bs.w, 0.f));
      *(short4v*)&E[(mt * 16 + mrow) * LDSW + oc] = s;
    }
  }
}

// ---------------- prep: convert weights to bf16 in workspace ----------------
__global__ void prep_kernel(const float* __restrict__ Wa, const float* __restrict__ Wb,
                            const float* __restrict__ Wca, const float* __restrict__ Wcb,
                            const float* __restrict__ Wcc, const float* __restrict__ Wout,
                            short* __restrict__ outS) {
  const int tid = blockIdx.x * blockDim.x + threadIdx.x;
  const int stride = gridDim.x * blockDim.x;
  const int M = 262144;
  for (int i = tid; i < 6 * M + 1024; i += stride) {
    float x;
    if (i < M) x = Wa[i];
    else if (i < 2 * M) x = Wb[i - M];
    else if (i < 3 * M) { const int t = i - 2 * M; x = Wca[(t >> 9) * 1024 + (t & 511)]; }
    else if (i < 4 * M) { const int t = i - 3 * M; x = Wca[(t >> 9) * 1024 + 512 + (t & 511)]; }
    else if (i < 5 * M) x = Wcb[i - 4 * M];
    else if (i < 6 * M) x = Wcc[i - 5 * M];
    else x = Wout[i - 6 * M];
    outS[i] = (short)f2bf(x);
  }
}

// ---------------- node stage: 3 per-layer tiled kernels (64 rows x 64 cols) ---
// MODE 1: X=bv fp32, out = relu(X@Wa^T + xy-term + ba + bxy) -> bf16
// MODE 2: X=f1 bf16, out = relu(X@Wb^T + bb) -> bf16
// MODE 3: X=f2 bf16, out = X@Wuv^T (1024 cols) -> fp32 u (cols<512) / v (>=512)
template <int MODE>
__global__ __launch_bounds__(256, 4) void node_layer(
    const void* __restrict__ Xin, const short* __restrict__ W,
    const float* __restrict__ bias, const float* __restrict__ xy,
    const float* __restrict__ Wxy, const float* __restrict__ bxy,
    void* __restrict__ Yout, float* __restrict__ vout, int colTiles) {
  __shared__ short X[64 * LDSW];
  __shared__ float xyl[128];
  const int tid = threadIdx.x, lane = tid & 63, wave = tid >> 6;
  const int rt = blockIdx.x / colTiles, ct = blockIdx.x % colTiles;
  const int row0 = rt * 64, c0 = ct * 64;

  if (MODE == 1) {
    const float* bv = (const float*)Xin;
    const int hc = (tid & 127) * 4, m0 = tid >> 7;
    for (int m = m0; m < 64; m += 2) {
      const float4 t = *(const float4*)(bv + (row0 + m) * 512 + hc);
      short4v s;
      s.x = (short)f2bf(t.x); s.y = (short)f2bf(t.y);
      s.z = (short)f2bf(t.z); s.w = (short)f2bf(t.w);
      *(short4v*)&X[m * LDSW + hc] = s;
    }
    if (tid < 128) xyl[tid] = xy[row0 * 2 + tid];
  } else {
    const short* xb = (const short*)Xin;
    const int hc = (tid & 63) * 8, m0 = tid >> 6;
    for (int m = m0; m < 64; m += 4)
      *(short8*)&X[m * LDSW + hc] = *(const short8*)(xb + (row0 + m) * 512 + hc);
  }
  __syncthreads();

  const int nbase = c0 + wave * 16;
  f32x4 acc[4][1];
  zero_acc<4, 1>(acc);
  gemm_kloop<4, 1>(X, W, lane, nbase, acc);

  const int mrow = lane & 15, kg = lane >> 4;
  const int oc = nbase + kg * 4;
  if (MODE == 3) {
    float* u = (float*)Yout;
#pragma unroll
    for (int mt = 0; mt < 4; ++mt) {
      const int row = row0 + mt * 16 + mrow;
      if (oc < 512) *(f32x4*)&u[row * 512 + oc] = acc[mt][0];     // block-uniform branch
      else          *(f32x4*)&vout[row * 512 + oc - 512] = acc[mt][0];
    }
  } else {
    short* Y = (short*)Yout;
    const float4 bs = *(const float4*)(bias + oc);
    float b2[4] = {0.f, 0.f, 0.f, 0.f}, w0[4], w1[4];
    if (MODE == 1) {
      const float4 t = *(const float4*)(bxy + oc);
      b2[0] = t.x; b2[1] = t.y; b2[2] = t.z; b2[3] = t.w;
#pragma unroll
      for (int r = 0; r < 4; ++r) { w0[r] = Wxy[(oc + r) * 2]; w1[r] = Wxy[(oc + r) * 2 + 1]; }
    }
#pragma unroll
    for (int mt = 0; mt < 4; ++mt) {
      const int row = mt * 16 + mrow;
      short4v s;
#pragma unroll
      for (int r = 0; r < 4; ++r) {
        float xv = acc[mt][0][r] + ((const float*)&bs)[r];
        if (MODE == 1) xv += b2[r] + xyl[row * 2] * w0[r] + xyl[row * 2 + 1] * w1[r];
        ((short*)&s)[r] = (short)f2bf(fmaxf(xv, 0.f));
      }
      *(short4v*)&Y[(row0 + row) * 512 + oc] = s;
    }
  }
}

// ---------------- edge stage: fused E0 -> E1 -> E2 -> out ----------------
// 144-row tiles (3 i x 48 j): LDS 158,976 B -> 1 block/CU, 8 waves.
// 1024 blocks = exactly 4 full rounds of 256 CUs. W/CU = 4.1 MB.
__global__ __launch_bounds__(512, 2) void edge_kernel(
    const float* __restrict__ u, const float* __restrict__ v,
    const short* __restrict__ Wcb, const short* __restrict__ Wcc,
    const short* __restrict__ Wout,
    const float* __restrict__ bca, const float* __restrict__ bcb,
    const float* __restrict__ bcc, const float* __restrict__ bout,
    float* __restrict__ out) {
  __shared__ short A[144 * LDSW];      // 149,760 B
  __shared__ float red[144 * 2 * 8];   //   9,216 B
  const int tid = threadIdx.x, lane = tid & 63, wave = tid >> 6;
  const int blk = blockIdx.x;
  const int b = blk >> 8, rem = blk & 255, ip = rem >> 2, jt = rem & 3;
  const float* urow0 = u + (b * 192 + jt * 48) * 512;        // row m: j = jt*48 + m%48
  const float* vrow0 = v + (b * 192 + ip * 3) * 512;         // row m: i = ip*3 + m/48

  {  // Phase 0: E0 = relu(u[j] + v[i] + b_ca) -> bf16 LDS
    const int hc = (tid & 127) * 4, m0 = tid >> 7;
    const float4 v0 = *(const float4*)(vrow0 + hc);
    const float4 v1 = *(const float4*)(vrow0 + 512 + hc);
    const float4 v2 = *(const float4*)(vrow0 + 1024 + hc);
    const float4 bb = *(const float4*)(bca + hc);
#pragma unroll 4
    for (int m = m0; m < 144; m += 4) {
      const int ii = (m >= 96) ? 2 : (m >= 48 ? 1 : 0);
      const int jj = m - ii * 48;
      const float4 vv = (ii == 0) ? v0 : (ii == 1) ? v1 : v2;
      const float4 uu = *(const float4*)(urow0 + jj * 512 + hc);
      short4v s;
      s.x = (short)f2bf(fmaxf(uu.x + vv.x + bb.x, 0.f));
      s.y = (short)f2bf(fmaxf(uu.y + vv.y + bb.y, 0.f));
      s.z = (short)f2bf(fmaxf(uu.z + vv.z + bb.z, 0.f));
      s.w = (short)f2bf(fmaxf(uu.w + vv.w + bb.w, 0.f));
      *(short4v*)&A[m * LDSW + hc] = s;
    }
  }
  __syncthreads();

  const int nbase = wave * 64;
  f32x4 acc[9][4];

  // layer cb
  zero_acc<9, 4>(acc);
  gemm_kloop<9, 4>(A, Wcb, lane, nbase, acc);
  __syncthreads();                 // all waves done reading E0
  store_relu_lds<9, 4>(A, bcb, lane, nbase, acc);
  __syncthreads();

  // layer cc
  zero_acc<9, 4>(acc);
  gemm_kloop<9, 4>(A, Wcc, lane, nbase, acc);
  __syncthreads();
  store_relu_lds<9, 4>(A, bcc, lane, nbase, acc);
  __syncthreads();

  // final: out = E2 @ Wout^T + bout.  k-split across 8 waves, n padded 2->16.
  f32x4 oacc[9];
#pragma unroll
  for (int mt = 0; mt < 9; ++mt) { f32x4 z = {0.f, 0.f, 0.f, 0.f}; oacc[mt] = z; }
  const int n = lane & 15, kg2 = lane >> 4;
#pragma unroll
  for (int kk = 0; kk < 2; ++kk) {
    const int k0 = wave * 64 + kk * 32 + kg2 * 8;
    short8 bf = {0, 0, 0, 0, 0, 0, 0, 0};
    if (n < 2) bf = *(const short8*)(Wout + n * 512 + k0);
#pragma unroll
    for (int mt = 0; mt < 9; ++mt) {
      const short8 af = *(const short8*)(A + (mt * 16 + n) * LDSW + k0);
      oacc[mt] = __builtin_amdgcn_mfma_f32_16x16x32_bf16(af, bf, oacc[mt], 0, 0, 0);
    }
  }
  if (n < 2) {
#pragma unroll
    for (int mt = 0; mt < 9; ++mt)
#pragma unroll
      for (int r = 0; r < 4; ++r) {
        const int row = mt * 16 + kg2 * 4 + r;
        red[(row * 2 + n) * 8 + wave] = oacc[mt][r];
      }
  }
  __syncthreads();
  if (tid < 288) {
    const int row = tid >> 1, o = tid & 1;
    float s = bout[o];
#pragma unroll
    for (int w = 0; w < 8; ++w) s += red[(row * 2 + o) * 8 + w];
    const int ii = (row >= 96) ? 2 : (row >= 48 ? 1 : 0);
    const int jj = row - ii * 48;
    out[((b * 192 + ip * 3 + ii) * 192 + jt * 48 + jj) * 2 + o] = s;
  }
}

extern "C" void kernel_launch(void* const* d_in, const int* in_sizes, int n_in,
                              void* d_out, int out_size, void* d_ws, size_t ws_size,
                              hipStream_t stream) {
  const float* bv   = (const float*)d_in[0];
  const float* xy   = (const float*)d_in[1];
  const float* Wxy  = (const float*)d_in[2];
  const float* bxy  = (const float*)d_in[3];
  const float* Wa   = (const float*)d_in[4];
  const float* ba   = (const float*)d_in[5];
  const float* Wb   = (const float*)d_in[6];
  const float* bb   = (const float*)d_in[7];
  const float* Wca  = (const float*)d_in[8];
  const float* bca  = (const float*)d_in[9];
  const float* Wcb  = (const float*)d_in[10];
  const float* bcb  = (const float*)d_in[11];
  const float* Wcc  = (const float*)d_in[12];
  const float* bcc  = (const float*)d_in[13];
  const float* Wout = (const float*)d_in[14];
  const float* bout = (const float*)d_in[15];
  float* out = (float*)d_out;

  // ws layout (bytes): [0, 3,147,776) bf16 weights;
  // f1 bf16 @3,147,776 (aliased by u fp32, f1 dead before L3 writes u);
  // f2 bf16 @4,720,640; v fp32 @5,507,072; end 7,079,936.
  short* S = (short*)d_ws;
  char* base = (char*)d_ws;
  short* WaB   = S;
  short* WbB   = S + 262144;
  short* WuvB  = S + 524288;    // [1024][512]: rows 0-511 = W1 (u), 512-1023 = W2 (v)
  short* WcbB  = S + 1048576;
  short* WccB  = S + 1310720;
  short* WoutB = S + 1572864;
  short* f1 = (short*)(base + 3147776);
  float* u  = (float*)(base + 3147776);
  short* f2 = (short*)(base + 4720640);
  float* v  = (float*)(base + 5507072);

  prep_kernel<<<512, 256, 0, stream>>>(Wa, Wb, Wca, Wcb, Wcc, Wout, S);
  node_layer<1><<<96, 256, 0, stream>>>(bv, WaB, ba, xy, Wxy, bxy, f1, nullptr, 8);
  node_layer<2><<<96, 256, 0, stream>>>(f1, WbB, bb, nullptr, nullptr, nullptr, f2, nullptr, 8);
  node_layer<3><<<192, 256, 0, stream>>>(f2, WuvB, nullptr, nullptr, nullptr, nullptr, u, v, 16);
  edge_kernel<<<1024, 512, 0, stream>>>(u, v, WcbB, WccB, WoutB, bca, bcb, bcc, bout, out);
}

// Round 6
// 294.963 us; speedup vs baseline: 1.4603x; 1.0173x over previous
//
#include <hip/hip_runtime.h>

// BrickVectorEdgeModel on MI355X (gfx950).
// R6: R5 structure (144-row edge tiles, 1024 blocks = 4 full CU-rounds,
// W/CU 4.1 MB) with the spill fixed: eF is JIT-loaded per m-tile with a
// 1-deep rotating prefetch (2 live regs instead of 9x4), wF keeps its
// global double-buffer. Budget: acc 144 AGPR + wF 32 + eF 16 + addr ~20
// = ~212 <= 256 at 2 waves/SIMD. Canary: WRITE_SIZE must drop 29MB -> 1.2MB.

typedef short  short8  __attribute__((ext_vector_type(8)));
typedef short  short4v __attribute__((ext_vector_type(4)));
typedef float  f32x4   __attribute__((ext_vector_type(4)));

#define LDSW 520   // LDS row stride in bf16 elems (520*2B = 1040B, 16B-aligned)

__device__ inline unsigned short f2bf(float x) {
  unsigned u = __float_as_uint(x);
  unsigned r = (u + 0x7FFFu + ((u >> 16) & 1u)) >> 16;  // RNE
  return (unsigned short)r;
}

template <int MT, int NT>
__device__ inline void zero_acc(f32x4 (&acc)[MT][NT]) {
#pragma unroll
  for (int mt = 0; mt < MT; ++mt)
#pragma unroll
    for (int nt = 0; nt < NT; ++nt) {
      f32x4 z = {0.f, 0.f, 0.f, 0.f};
      acc[mt][nt] = z;
    }
}

// acc[mt][nt] (+)= W-tile x E-tile.  W as MFMA A-operand (m = out-col),
// E as B-operand (n = edge-row).  Lane holds 4 consecutive out-cols
// (kg*4+r) at edge-row (mt*16 + (lane&15)).
// wF (global, ~200-300cyc) register double-buffered across ks.
// eF (LDS, ~12cyc) JIT per m-tile with 1-deep rotating prefetch: only 2 live.
template <int MT, int NT>
__device__ inline void gemm_kloop(const short* E, const short* __restrict__ W,
                                  int lane, int nbase, f32x4 (&acc)[MT][NT]) {
  const int mrow = lane & 15, kg = lane >> 4;
  const short* El = E + mrow * LDSW + kg * 8;
  const short* Wl = W + (nbase + mrow) * 512 + kg * 8;
  short8 wF[2][NT];
#pragma unroll
  for (int nt = 0; nt < NT; ++nt) wF[0][nt] = *(const short8*)(Wl + nt * 16 * 512);
#pragma unroll
  for (int ks = 0; ks < 16; ++ks) {
    const int cur = ks & 1, nxt = cur ^ 1;
    if (ks < 15) {
      const int k1 = (ks + 1) * 32;
#pragma unroll
      for (int nt = 0; nt < NT; ++nt)
        wF[nxt][nt] = *(const short8*)(Wl + nt * 16 * 512 + k1);
    }
    const int k0 = ks * 32;
    short8 e0 = *(const short8*)(El + k0);
#pragma unroll
    for (int mt = 0; mt < MT; ++mt) {
      const short8 ecur = e0;
      if (mt < MT - 1) e0 = *(const short8*)(El + (mt + 1) * 16 * LDSW + k0);
#pragma unroll
      for (int nt = 0; nt < NT; ++nt)
        acc[mt][nt] = __builtin_amdgcn_mfma_f32_16x16x32_bf16(
            wF[cur][nt], ecur, acc[mt][nt], 0, 0, 0);
    }
  }
}

// relu(acc + bias[outcol]) -> bf16 -> LDS, 8B vector writes.
template <int MT, int NT>
__device__ inline void store_relu_lds(short* E, const float* __restrict__ bias,
                                      int lane, int nbase, f32x4 (&acc)[MT][NT]) {
  const int mrow = lane & 15, kg = lane >> 4;
#pragma unroll
  for (int nt = 0; nt < NT; ++nt) {
    const int oc = nbase + nt * 16 + kg * 4;
    const float4 bs = *(const float4*)(bias + oc);
#pragma unroll
    for (int mt = 0; mt < MT; ++mt) {
      short4v s;
      s.x = (short)f2bf(fmaxf(acc[mt][nt][0] + bs.x, 0.f));
      s.y = (short)f2bf(fmaxf(acc[mt][nt][1] + bs.y, 0.f));
      s.z = (short)f2bf(fmaxf(acc[mt][nt][2] + bs.z, 0.f));
      s.w = (short)f2bf(fmaxf(acc[mt][nt][3] + bs.w, 0.f));
      *(short4v*)&E[(mt * 16 + mrow) * LDSW + oc] = s;
    }
  }
}

// ---------------- prep: convert weights to bf16 in workspace ----------------
__global__ void prep_kernel(const float* __restrict__ Wa, const float* __restrict__ Wb,
                            const float* __restrict__ Wca, const float* __restrict__ Wcb,
                            const float* __restrict__ Wcc, const float* __restrict__ Wout,
                            short* __restrict__ outS) {
  const int tid = blockIdx.x * blockDim.x + threadIdx.x;
  const int stride = gridDim.x * blockDim.x;
  const int M = 262144;
  for (int i = tid; i < 6 * M + 1024; i += stride) {
    float x;
    if (i < M) x = Wa[i];
    else if (i < 2 * M) x = Wb[i - M];
    else if (i < 3 * M) { const int t = i - 2 * M; x = Wca[(t >> 9) * 1024 + (t & 511)]; }
    else if (i < 4 * M) { const int t = i - 3 * M; x = Wca[(t >> 9) * 1024 + 512 + (t & 511)]; }
    else if (i < 5 * M) x = Wcb[i - 4 * M];
    else if (i < 6 * M) x = Wcc[i - 5 * M];
    else x = Wout[i - 6 * M];
    outS[i] = (short)f2bf(x);
  }
}

// ---------------- node stage: 3 per-layer tiled kernels (64 rows x 64 cols) ---
// MODE 1: X=bv fp32, out = relu(X@Wa^T + xy-term + ba + bxy) -> bf16
// MODE 2: X=f1 bf16, out = relu(X@Wb^T + bb) -> bf16
// MODE 3: X=f2 bf16, out = X@Wuv^T (1024 cols) -> fp32 u (cols<512) / v (>=512)
template <int MODE>
__global__ __launch_bounds__(256, 4) void node_layer(
    const void* __restrict__ Xin, const short* __restrict__ W,
    const float* __restrict__ bias, const float* __restrict__ xy,
    const float* __restrict__ Wxy, const float* __restrict__ bxy,
    void* __restrict__ Yout, float* __restrict__ vout, int colTiles) {
  __shared__ short X[64 * LDSW];
  __shared__ float xyl[128];
  const int tid = threadIdx.x, lane = tid & 63, wave = tid >> 6;
  const int rt = blockIdx.x / colTiles, ct = blockIdx.x % colTiles;
  const int row0 = rt * 64, c0 = ct * 64;

  if (MODE == 1) {
    const float* bv = (const float*)Xin;
    const int hc = (tid & 127) * 4, m0 = tid >> 7;
    for (int m = m0; m < 64; m += 2) {
      const float4 t = *(const float4*)(bv + (row0 + m) * 512 + hc);
      short4v s;
      s.x = (short)f2bf(t.x); s.y = (short)f2bf(t.y);
      s.z = (short)f2bf(t.z); s.w = (short)f2bf(t.w);
      *(short4v*)&X[m * LDSW + hc] = s;
    }
    if (tid < 128) xyl[tid] = xy[row0 * 2 + tid];
  } else {
    const short* xb = (const short*)Xin;
    const int hc = (tid & 63) * 8, m0 = tid >> 6;
    for (int m = m0; m < 64; m += 4)
      *(short8*)&X[m * LDSW + hc] = *(const short8*)(xb + (row0 + m) * 512 + hc);
  }
  __syncthreads();

  const int nbase = c0 + wave * 16;
  f32x4 acc[4][1];
  zero_acc<4, 1>(acc);
  gemm_kloop<4, 1>(X, W, lane, nbase, acc);

  const int mrow = lane & 15, kg = lane >> 4;
  const int oc = nbase + kg * 4;
  if (MODE == 3) {
    float* u = (float*)Yout;
#pragma unroll
    for (int mt = 0; mt < 4; ++mt) {
      const int row = row0 + mt * 16 + mrow;
      if (oc < 512) *(f32x4*)&u[row * 512 + oc] = acc[mt][0];     // block-uniform branch
      else          *(f32x4*)&vout[row * 512 + oc - 512] = acc[mt][0];
    }
  } else {
    short* Y = (short*)Yout;
    const float4 bs = *(const float4*)(bias + oc);
    float b2[4] = {0.f, 0.f, 0.f, 0.f}, w0[4], w1[4];
    if (MODE == 1) {
      const float4 t = *(const float4*)(bxy + oc);
      b2[0] = t.x; b2[1] = t.y; b2[2] = t.z; b2[3] = t.w;
#pragma unroll
      for (int r = 0; r < 4; ++r) { w0[r] = Wxy[(oc + r) * 2]; w1[r] = Wxy[(oc + r) * 2 + 1]; }
    }
#pragma unroll
    for (int mt = 0; mt < 4; ++mt) {
      const int row = mt * 16 + mrow;
      short4v s;
#pragma unroll
      for (int r = 0; r < 4; ++r) {
        float xv = acc[mt][0][r] + ((const float*)&bs)[r];
        if (MODE == 1) xv += b2[r] + xyl[row * 2] * w0[r] + xyl[row * 2 + 1] * w1[r];
        ((short*)&s)[r] = (short)f2bf(fmaxf(xv, 0.f));
      }
      *(short4v*)&Y[(row0 + row) * 512 + oc] = s;
    }
  }
}

// ---------------- edge stage: fused E0 -> E1 -> E2 -> out ----------------
// 144-row tiles (3 i x 48 j): LDS 158,976 B -> 1 block/CU, 8 waves.
// 1024 blocks = exactly 4 full rounds of 256 CUs. W/CU = 4.1 MB.
__global__ __launch_bounds__(512, 2) void edge_kernel(
    const float* __restrict__ u, const float* __restrict__ v,
    const short* __restrict__ Wcb, const short* __restrict__ Wcc,
    const short* __restrict__ Wout,
    const float* __restrict__ bca, const float* __restrict__ bcb,
    const float* __restrict__ bcc, const float* __restrict__ bout,
    float* __restrict__ out) {
  __shared__ short A[144 * LDSW];      // 149,760 B
  __shared__ float red[144 * 2 * 8];   //   9,216 B
  const int tid = threadIdx.x, lane = tid & 63, wave = tid >> 6;
  const int blk = blockIdx.x;
  const int b = blk >> 8, rem = blk & 255, ip = rem >> 2, jt = rem & 3;
  const float* urow0 = u + (b * 192 + jt * 48) * 512;        // row m: j = jt*48 + m%48
  const float* vrow0 = v + (b * 192 + ip * 3) * 512;         // row m: i = ip*3 + m/48

  {  // Phase 0: E0 = relu(u[j] + v[i] + b_ca) -> bf16 LDS
    const int hc = (tid & 127) * 4, m0 = tid >> 7;
    const float4 v0 = *(const float4*)(vrow0 + hc);
    const float4 v1 = *(const float4*)(vrow0 + 512 + hc);
    const float4 v2 = *(const float4*)(vrow0 + 1024 + hc);
    const float4 bb = *(const float4*)(bca + hc);
#pragma unroll 4
    for (int m = m0; m < 144; m += 4) {
      const int ii = (m >= 96) ? 2 : (m >= 48 ? 1 : 0);
      const int jj = m - ii * 48;
      const float4 vv = (ii == 0) ? v0 : (ii == 1) ? v1 : v2;
      const float4 uu = *(const float4*)(urow0 + jj * 512 + hc);
      short4v s;
      s.x = (short)f2bf(fmaxf(uu.x + vv.x + bb.x, 0.f));
      s.y = (short)f2bf(fmaxf(uu.y + vv.y + bb.y, 0.f));
      s.z = (short)f2bf(fmaxf(uu.z + vv.z + bb.z, 0.f));
      s.w = (short)f2bf(fmaxf(uu.w + vv.w + bb.w, 0.f));
      *(short4v*)&A[m * LDSW + hc] = s;
    }
  }
  __syncthreads();

  const int nbase = wave * 64;
  f32x4 acc[9][4];

  // layer cb
  zero_acc<9, 4>(acc);
  gemm_kloop<9, 4>(A, Wcb, lane, nbase, acc);
  __syncthreads();                 // all waves done reading E0
  store_relu_lds<9, 4>(A, bcb, lane, nbase, acc);
  __syncthreads();

  // layer cc
  zero_acc<9, 4>(acc);
  gemm_kloop<9, 4>(A, Wcc, lane, nbase, acc);
  __syncthreads();
  store_relu_lds<9, 4>(A, bcc, lane, nbase, acc);
  __syncthreads();

  // final: out = E2 @ Wout^T + bout.  k-split across 8 waves, n padded 2->16.
  f32x4 oacc[9];
#pragma unroll
  for (int mt = 0; mt < 9; ++mt) { f32x4 z = {0.f, 0.f, 0.f, 0.f}; oacc[mt] = z; }
  const int n = lane & 15, kg2 = lane >> 4;
#pragma unroll
  for (int kk = 0; kk < 2; ++kk) {
    const int k0 = wave * 64 + kk * 32 + kg2 * 8;
    short8 bf = {0, 0, 0, 0, 0, 0, 0, 0};
    if (n < 2) bf = *(const short8*)(Wout + n * 512 + k0);
#pragma unroll
    for (int mt = 0; mt < 9; ++mt) {
      const short8 af = *(const short8*)(A + (mt * 16 + n) * LDSW + k0);
      oacc[mt] = __builtin_amdgcn_mfma_f32_16x16x32_bf16(af, bf, oacc[mt], 0, 0, 0);
    }
  }
  if (n < 2) {
#pragma unroll
    for (int mt = 0; mt < 9; ++mt)
#pragma unroll
      for (int r = 0; r < 4; ++r) {
        const int row = mt * 16 + kg2 * 4 + r;
        red[(row * 2 + n) * 8 + wave] = oacc[mt][r];
      }
  }
  __syncthreads();
  if (tid < 288) {
    const int row = tid >> 1, o = tid & 1;
    float s = bout[o];
#pragma unroll
    for (int w = 0; w < 8; ++w) s += red[(row * 2 + o) * 8 + w];
    const int ii = (row >= 96) ? 2 : (row >= 48 ? 1 : 0);
    const int jj = row - ii * 48;
    out[((b * 192 + ip * 3 + ii) * 192 + jt * 48 + jj) * 2 + o] = s;
  }
}

extern "C" void kernel_launch(void* const* d_in, const int* in_sizes, int n_in,
                              void* d_out, int out_size, void* d_ws, size_t ws_size,
                              hipStream_t stream) {
  const float* bv   = (const float*)d_in[0];
  const float* xy   = (const float*)d_in[1];
  const float* Wxy  = (const float*)d_in[2];
  const float* bxy  = (const float*)d_in[3];
  const float* Wa   = (const float*)d_in[4];
  const float* ba   = (const float*)d_in[5];
  const float* Wb   = (const float*)d_in[6];
  const float* bb   = (const float*)d_in[7];
  const float* Wca  = (const float*)d_in[8];
  const float* bca  = (const float*)d_in[9];
  const float* Wcb  = (const float*)d_in[10];
  const float* bcb  = (const float*)d_in[11];
  const float* Wcc  = (const float*)d_in[12];
  const float* bcc  = (const float*)d_in[13];
  const float* Wout = (const float*)d_in[14];
  const float* bout = (const float*)d_in[15];
  float* out = (float*)d_out;

  // ws layout (bytes): [0, 3,147,776) bf16 weights;
  // f1 bf16 @3,147,776 (aliased by u fp32, f1 dead before L3 writes u);
  // f2 bf16 @4,720,640; v fp32 @5,507,072; end 7,079,936.
  short* S = (short*)d_ws;
  char* base = (char*)d_ws;
  short* WaB   = S;
  short* WbB   = S + 262144;
  short* WuvB  = S + 524288;    // [1024][512]: rows 0-511 = W1 (u), 512-1023 = W2 (v)
  short* WcbB  = S + 1048576;
  short* WccB  = S + 1310720;
  short* WoutB = S + 1572864;
  short* f1 = (short*)(base + 3147776);
  float* u  = (float*)(base + 3147776);
  short* f2 = (short*)(base + 4720640);
  float* v  = (float*)(base + 5507072);

  prep_kernel<<<512, 256, 0, stream>>>(Wa, Wb, Wca, Wcb, Wcc, Wout, S);
  node_layer<1><<<96, 256, 0, stream>>>(bv, WaB, ba, xy, Wxy, bxy, f1, nullptr, 8);
  node_layer<2><<<96, 256, 0, stream>>>(f1, WbB, bb, nullptr, nullptr, nullptr, f2, nullptr, 8);
  node_layer<3><<<192, 256, 0, stream>>>(f2, WuvB, nullptr, nullptr, nullptr, nullptr, u, v, 16);
  edge_kernel<<<1024, 512, 0, stream>>>(u, v, WcbB, WccB, WoutB, bca, bcb, bcc, bout, out);
}

// Round 7
// 259.056 us; speedup vs baseline: 1.6627x; 1.1386x over previous
//
#include <hip/hip_runtime.h>

// BrickVectorEdgeModel on MI355X (gfx950).
// R7: W-relayout attack. Model from R1-R6: edge time = 119us + 21us/MB of
// W-from-L2 per CU; the 21us/MB is a request-rate limit (16 half-used cache
// lines per wF instr at stride 1024B). Fix: prep repacks each GEMM weight
// into (col_tile, k_step)-tiled 1KB fragments so every wF load is one
// perfectly-coalesced 1KB wave read, streaming sequentially over k.
// Tiled W layout (per 512-col weight, elems): off(c,k) =
//   ((c>>4)*16 + (k>>5))*512 + (c&15)*32 + (k&31)

typedef short  short8  __attribute__((ext_vector_type(8)));
typedef short  short4v __attribute__((ext_vector_type(4)));
typedef float  f32x4   __attribute__((ext_vector_type(4)));

#define LDSW 520   // LDS row stride in bf16 elems (520*2B = 1040B, 16B-aligned)

__device__ inline unsigned short f2bf(float x) {
  unsigned u = __float_as_uint(x);
  unsigned r = (u + 0x7FFFu + ((u >> 16) & 1u)) >> 16;  // RNE
  return (unsigned short)r;
}

__device__ __host__ inline int wtile_off(int c, int k) {
  return ((c >> 4) * 16 + (k >> 5)) * 512 + (c & 15) * 32 + (k & 31);
}

template <int MT, int NT>
__device__ inline void zero_acc(f32x4 (&acc)[MT][NT]) {
#pragma unroll
  for (int mt = 0; mt < MT; ++mt)
#pragma unroll
    for (int nt = 0; nt < NT; ++nt) {
      f32x4 z = {0.f, 0.f, 0.f, 0.f};
      acc[mt][nt] = z;
    }
}

// acc[mt][nt] (+)= W-tile x E-tile.  W as MFMA A-operand (m = out-col),
// E as B-operand (n = edge-row).  Lane holds 4 consecutive out-cols
// (kg*4+r) at edge-row (mt*16 + (lane&15)).
// W is in tiled layout: per (col_tile ct, ks) a contiguous 1KB fragment;
// lane's slice at (lane&15)*32 + (lane>>4)*8.  One wF load = coalesced 1KB.
// wF register double-buffered across ks; eF JIT from LDS, rotating 1-deep.
template <int MT, int NT>
__device__ inline void gemm_kloop(const short* E, const short* __restrict__ W,
                                  int lane, int nbase, f32x4 (&acc)[MT][NT]) {
  const int mrow = lane & 15, kg = lane >> 4;
  const short* El = E + mrow * LDSW + kg * 8;
  const short* Wl = W + (nbase >> 4) * 8192 + mrow * 32 + kg * 8;
  short8 wF[2][NT];
#pragma unroll
  for (int nt = 0; nt < NT; ++nt) wF[0][nt] = *(const short8*)(Wl + nt * 8192);
#pragma unroll
  for (int ks = 0; ks < 16; ++ks) {
    const int cur = ks & 1, nxt = cur ^ 1;
    if (ks < 15) {
      const int k1 = (ks + 1) * 512;
#pragma unroll
      for (int nt = 0; nt < NT; ++nt)
        wF[nxt][nt] = *(const short8*)(Wl + nt * 8192 + k1);
    }
    const int k0 = ks * 32;
    short8 e0 = *(const short8*)(El + k0);
#pragma unroll
    for (int mt = 0; mt < MT; ++mt) {
      const short8 ecur = e0;
      if (mt < MT - 1) e0 = *(const short8*)(El + (mt + 1) * 16 * LDSW + k0);
#pragma unroll
      for (int nt = 0; nt < NT; ++nt)
        acc[mt][nt] = __builtin_amdgcn_mfma_f32_16x16x32_bf16(
            wF[cur][nt], ecur, acc[mt][nt], 0, 0, 0);
    }
  }
}

// relu(acc + bias[outcol]) -> bf16 -> LDS, 8B vector writes.
template <int MT, int NT>
__device__ inline void store_relu_lds(short* E, const float* __restrict__ bias,
                                      int lane, int nbase, f32x4 (&acc)[MT][NT]) {
  const int mrow = lane & 15, kg = lane >> 4;
#pragma unroll
  for (int nt = 0; nt < NT; ++nt) {
    const int oc = nbase + nt * 16 + kg * 4;
    const float4 bs = *(const float4*)(bias + oc);
#pragma unroll
    for (int mt = 0; mt < MT; ++mt) {
      short4v s;
      s.x = (short)f2bf(fmaxf(acc[mt][nt][0] + bs.x, 0.f));
      s.y = (short)f2bf(fmaxf(acc[mt][nt][1] + bs.y, 0.f));
      s.z = (short)f2bf(fmaxf(acc[mt][nt][2] + bs.z, 0.f));
      s.w = (short)f2bf(fmaxf(acc[mt][nt][3] + bs.w, 0.f));
      *(short4v*)&E[(mt * 16 + mrow) * LDSW + oc] = s;
    }
  }
}

// ---------------- prep: fp32 -> bf16 + tiled relayout ----------------
__global__ void prep_kernel(const float* __restrict__ Wa, const float* __restrict__ Wb,
                            const float* __restrict__ Wca, const float* __restrict__ Wcb,
                            const float* __restrict__ Wcc, const float* __restrict__ Wout,
                            short* __restrict__ outS) {
  const int tid = blockIdx.x * blockDim.x + threadIdx.x;
  const int stride = gridDim.x * blockDim.x;
  const int M = 262144;
  for (int i = tid; i < 6 * M + 1024; i += stride) {
    float x;
    int dst;
    if (i < M) {                       // WaB tiled
      const int c = i >> 9, k = i & 511;
      x = Wa[i];
      dst = wtile_off(c, k);
    } else if (i < 2 * M) {            // WbB tiled
      const int t = i - M, c = t >> 9, k = t & 511;
      x = Wb[t];
      dst = M + wtile_off(c, k);
    } else if (i < 3 * M) {            // Wuv: u-half, tiled cols 0..511
      const int t = i - 2 * M, c = t >> 9, k = t & 511;
      x = Wca[c * 1024 + k];
      dst = 2 * M + wtile_off(c, k);
    } else if (i < 4 * M) {            // Wuv: v-half, tiled cols 512..1023
      const int t = i - 3 * M, c = t >> 9, k = t & 511;
      x = Wca[c * 1024 + 512 + k];
      dst = 2 * M + wtile_off(512 + c, k);
    } else if (i < 5 * M) {            // WcbB tiled
      const int t = i - 4 * M, c = t >> 9, k = t & 511;
      x = Wcb[t];
      dst = 4 * M + wtile_off(c, k);
    } else if (i < 6 * M) {            // WccB tiled
      const int t = i - 5 * M, c = t >> 9, k = t & 511;
      x = Wcc[t];
      dst = 5 * M + wtile_off(c, k);
    } else {                           // Wout plain row-major
      x = Wout[i - 6 * M];
      dst = i;
    }
    outS[dst] = (short)f2bf(x);
  }
}

// ---------------- node stage: 3 per-layer tiled kernels (64 rows x 64 cols) ---
// MODE 1: X=bv fp32, out = relu(X@Wa^T + xy-term + ba + bxy) -> bf16
// MODE 2: X=f1 bf16, out = relu(X@Wb^T + bb) -> bf16
// MODE 3: X=f2 bf16, out = X@Wuv^T (1024 cols) -> fp32 u (cols<512) / v (>=512)
template <int MODE>
__global__ __launch_bounds__(256, 4) void node_layer(
    const void* __restrict__ Xin, const short* __restrict__ W,
    const float* __restrict__ bias, const float* __restrict__ xy,
    const float* __restrict__ Wxy, const float* __restrict__ bxy,
    void* __restrict__ Yout, float* __restrict__ vout, int colTiles) {
  __shared__ short X[64 * LDSW];
  __shared__ float xyl[128];
  const int tid = threadIdx.x, lane = tid & 63, wave = tid >> 6;
  const int rt = blockIdx.x / colTiles, ct = blockIdx.x % colTiles;
  const int row0 = rt * 64, c0 = ct * 64;

  if (MODE == 1) {
    const float* bv = (const float*)Xin;
    const int hc = (tid & 127) * 4, m0 = tid >> 7;
    for (int m = m0; m < 64; m += 2) {
      const float4 t = *(const float4*)(bv + (row0 + m) * 512 + hc);
      short4v s;
      s.x = (short)f2bf(t.x); s.y = (short)f2bf(t.y);
      s.z = (short)f2bf(t.z); s.w = (short)f2bf(t.w);
      *(short4v*)&X[m * LDSW + hc] = s;
    }
    if (tid < 128) xyl[tid] = xy[row0 * 2 + tid];
  } else {
    const short* xb = (const short*)Xin;
    const int hc = (tid & 63) * 8, m0 = tid >> 6;
    for (int m = m0; m < 64; m += 4)
      *(short8*)&X[m * LDSW + hc] = *(const short8*)(xb + (row0 + m) * 512 + hc);
  }
  __syncthreads();

  const int nbase = c0 + wave * 16;
  f32x4 acc[4][1];
  zero_acc<4, 1>(acc);
  gemm_kloop<4, 1>(X, W, lane, nbase, acc);

  const int mrow = lane & 15, kg = lane >> 4;
  const int oc = nbase + kg * 4;
  if (MODE == 3) {
    float* u = (float*)Yout;
#pragma unroll
    for (int mt = 0; mt < 4; ++mt) {
      const int row = row0 + mt * 16 + mrow;
      if (oc < 512) *(f32x4*)&u[row * 512 + oc] = acc[mt][0];     // block-uniform branch
      else          *(f32x4*)&vout[row * 512 + oc - 512] = acc[mt][0];
    }
  } else {
    short* Y = (short*)Yout;
    const float4 bs = *(const float4*)(bias + oc);
    float b2[4] = {0.f, 0.f, 0.f, 0.f}, w0[4], w1[4];
    if (MODE == 1) {
      const float4 t = *(const float4*)(bxy + oc);
      b2[0] = t.x; b2[1] = t.y; b2[2] = t.z; b2[3] = t.w;
#pragma unroll
      for (int r = 0; r < 4; ++r) { w0[r] = Wxy[(oc + r) * 2]; w1[r] = Wxy[(oc + r) * 2 + 1]; }
    }
#pragma unroll
    for (int mt = 0; mt < 4; ++mt) {
      const int row = mt * 16 + mrow;
      short4v s;
#pragma unroll
      for (int r = 0; r < 4; ++r) {
        float xv = acc[mt][0][r] + ((const float*)&bs)[r];
        if (MODE == 1) xv += b2[r] + xyl[row * 2] * w0[r] + xyl[row * 2 + 1] * w1[r];
        ((short*)&s)[r] = (short)f2bf(fmaxf(xv, 0.f));
      }
      *(short4v*)&Y[(row0 + row) * 512 + oc] = s;
    }
  }
}

// ---------------- edge stage: fused E0 -> E1 -> E2 -> out ----------------
// 144-row tiles (3 i x 48 j): LDS 158,976 B -> 1 block/CU, 8 waves.
// 1024 blocks = exactly 4 full rounds of 256 CUs. W/CU = 4.1 MB.
__global__ __launch_bounds__(512, 2) void edge_kernel(
    const float* __restrict__ u, const float* __restrict__ v,
    const short* __restrict__ Wcb, const short* __restrict__ Wcc,
    const short* __restrict__ Wout,
    const float* __restrict__ bca, const float* __restrict__ bcb,
    const float* __restrict__ bcc, const float* __restrict__ bout,
    float* __restrict__ out) {
  __shared__ short A[144 * LDSW];      // 149,760 B
  __shared__ float red[144 * 2 * 8];   //   9,216 B
  const int tid = threadIdx.x, lane = tid & 63, wave = tid >> 6;
  const int blk = blockIdx.x;
  const int b = blk >> 8, rem = blk & 255, ip = rem >> 2, jt = rem & 3;
  const float* urow0 = u + (b * 192 + jt * 48) * 512;        // row m: j = jt*48 + m%48
  const float* vrow0 = v + (b * 192 + ip * 3) * 512;         // row m: i = ip*3 + m/48

  {  // Phase 0: E0 = relu(u[j] + v[i] + b_ca) -> bf16 LDS
    const int hc = (tid & 127) * 4, m0 = tid >> 7;
    const float4 v0 = *(const float4*)(vrow0 + hc);
    const float4 v1 = *(const float4*)(vrow0 + 512 + hc);
    const float4 v2 = *(const float4*)(vrow0 + 1024 + hc);
    const float4 bb = *(const float4*)(bca + hc);
#pragma unroll 4
    for (int m = m0; m < 144; m += 4) {
      const int ii = (m >= 96) ? 2 : (m >= 48 ? 1 : 0);
      const int jj = m - ii * 48;
      const float4 vv = (ii == 0) ? v0 : (ii == 1) ? v1 : v2;
      const float4 uu = *(const float4*)(urow0 + jj * 512 + hc);
      short4v s;
      s.x = (short)f2bf(fmaxf(uu.x + vv.x + bb.x, 0.f));
      s.y = (short)f2bf(fmaxf(uu.y + vv.y + bb.y, 0.f));
      s.z = (short)f2bf(fmaxf(uu.z + vv.z + bb.z, 0.f));
      s.w = (short)f2bf(fmaxf(uu.w + vv.w + bb.w, 0.f));
      *(short4v*)&A[m * LDSW + hc] = s;
    }
  }
  __syncthreads();

  const int nbase = wave * 64;
  f32x4 acc[9][4];

  // layer cb
  zero_acc<9, 4>(acc);
  gemm_kloop<9, 4>(A, Wcb, lane, nbase, acc);
  __syncthreads();                 // all waves done reading E0
  store_relu_lds<9, 4>(A, bcb, lane, nbase, acc);
  __syncthreads();

  // layer cc
  zero_acc<9, 4>(acc);
  gemm_kloop<9, 4>(A, Wcc, lane, nbase, acc);
  __syncthreads();
  store_relu_lds<9, 4>(A, bcc, lane, nbase, acc);
  __syncthreads();

  // final: out = E2 @ Wout^T + bout.  k-split across 8 waves, n padded 2->16.
  f32x4 oacc[9];
#pragma unroll
  for (int mt = 0; mt < 9; ++mt) { f32x4 z = {0.f, 0.f, 0.f, 0.f}; oacc[mt] = z; }
  const int n = lane & 15, kg2 = lane >> 4;
#pragma unroll
  for (int kk = 0; kk < 2; ++kk) {
    const int k0 = wave * 64 + kk * 32 + kg2 * 8;
    short8 bf = {0, 0, 0, 0, 0, 0, 0, 0};
    if (n < 2) bf = *(const short8*)(Wout + n * 512 + k0);
#pragma unroll
    for (int mt = 0; mt < 9; ++mt) {
      const short8 af = *(const short8*)(A + (mt * 16 + n) * LDSW + k0);
      oacc[mt] = __builtin_amdgcn_mfma_f32_16x16x32_bf16(af, bf, oacc[mt], 0, 0, 0);
    }
  }
  if (n < 2) {
#pragma unroll
    for (int mt = 0; mt < 9; ++mt)
#pragma unroll
      for (int r = 0; r < 4; ++r) {
        const int row = mt * 16 + kg2 * 4 + r;
        red[(row * 2 + n) * 8 + wave] = oacc[mt][r];
      }
  }
  __syncthreads();
  if (tid < 288) {
    const int row = tid >> 1, o = tid & 1;
    float s = bout[o];
#pragma unroll
    for (int w = 0; w < 8; ++w) s += red[(row * 2 + o) * 8 + w];
    const int ii = (row >= 96) ? 2 : (row >= 48 ? 1 : 0);
    const int jj = row - ii * 48;
    out[((b * 192 + ip * 3 + ii) * 192 + jt * 48 + jj) * 2 + o] = s;
  }
}

extern "C" void kernel_launch(void* const* d_in, const int* in_sizes, int n_in,
                              void* d_out, int out_size, void* d_ws, size_t ws_size,
                              hipStream_t stream) {
  const float* bv   = (const float*)d_in[0];
  const float* xy   = (const float*)d_in[1];
  const float* Wxy  = (const float*)d_in[2];
  const float* bxy  = (const float*)d_in[3];
  const float* Wa   = (const float*)d_in[4];
  const float* ba   = (const float*)d_in[5];
  const float* Wb   = (const float*)d_in[6];
  const float* bb   = (const float*)d_in[7];
  const float* Wca  = (const float*)d_in[8];
  const float* bca  = (const float*)d_in[9];
  const float* Wcb  = (const float*)d_in[10];
  const float* bcb  = (const float*)d_in[11];
  const float* Wcc  = (const float*)d_in[12];
  const float* bcc  = (const float*)d_in[13];
  const float* Wout = (const float*)d_in[14];
  const float* bout = (const float*)d_in[15];
  float* out = (float*)d_out;

  // ws layout (bytes): [0, 3,147,776) bf16 weights (tiled layout);
  // f1 bf16 @3,147,776 (aliased by u fp32, f1 dead before L3 writes u);
  // f2 bf16 @4,720,640; v fp32 @5,507,072; end 7,079,936.
  short* S = (short*)d_ws;
  char* base = (char*)d_ws;
  short* WaB   = S;
  short* WbB   = S + 262144;
  short* WuvB  = S + 524288;    // tiled, 1024 cols: ct 0-31 = W1 (u), 32-63 = W2 (v)
  short* WcbB  = S + 1048576;
  short* WccB  = S + 1310720;
  short* WoutB = S + 1572864;
  short* f1 = (short*)(base + 3147776);
  float* u  = (float*)(base + 3147776);
  short* f2 = (short*)(base + 4720640);
  float* v  = (float*)(base + 5507072);

  prep_kernel<<<512, 256, 0, stream>>>(Wa, Wb, Wca, Wcb, Wcc, Wout, S);
  node_layer<1><<<96, 256, 0, stream>>>(bv, WaB, ba, xy, Wxy, bxy, f1, nullptr, 8);
  node_layer<2><<<96, 256, 0, stream>>>(f1, WbB, bb, nullptr, nullptr, nullptr, f2, nullptr, 8);
  node_layer<3><<<192, 256, 0, stream>>>(f2, WuvB, nullptr, nullptr, nullptr, nullptr, u, v, 16);
  edge_kernel<<<1024, 512, 0, stream>>>(u, v, WcbB, WccB, WoutB, bca, bcb, bcc, bout, out);
}